// Round 6
// baseline (229.686 us; speedup 1.0000x reference)
//
#include <hip/hip_runtime.h>

// SplineFilter: out[b,n,f] = eval_x[b,n,f] * sf^2,
//   sf = sum_k basis_k(eigs[b,n]) * coeffs[k,f]
// Cubic B-spline over uniform knots linspace(0,2,16), 12 bases; only 4
// nonzero taps per x (cardinal cubic weights in t = x*7.5 - i).
//
// R5 post-mortem: every one-shot burst shape (LDS/L1 table, CHUNKS 2/4,
// 8k/16k blocks, ILP pins, max TLP) converges at kernel ~75-85 us
// (~3.6 TB/s = half the 6.29 TB/s copy ceiling). Remaining structural
// difference vs the copy kernel: burst waves spend ~70% of their life in
// pipeline fill and exit; a copy kernel is a STEADY-STATE grid-stride
// pipeline. This round: 2048 blocks x 256 thr x 16 iters/thread,
// software-pipelined (prefetch iter k+1's eigs+x before computing/storing
// iter k) so every wave keeps stream loads in flight continuously.
// NT load/store kept (R2 A/B: worth ~8 us). L1-resident 6 KB coeff table.

#define N_BASES 12
#define F_CH 128
#define THREADS 256
#define BLOCKS 2048            // 8 blocks/CU on 256 CUs
#define ROW_VF4 (F_CH / 4)     // 32 vf4 per coeff row

typedef float vf4 __attribute__((ext_vector_type(4)));

__device__ __forceinline__ vf4 eval_sf(float eg, int lane,
                                       const vf4* __restrict__ coeffs4) {
    // 4 nonzero cardinal cubic weights for x = eg.
    // Clamp u to [0,15]: keeps tt finite; per-tap select zeroes OOB taps.
    float u = eg * 7.5f;                    // x / (2/15)
    u = fminf(fmaxf(u, 0.0f), 15.0f);
    const int   i  = (int)u;
    const float tt = u - (float)i;
    const float t2  = tt * tt;
    const float t3  = t2 * tt;
    const float omt = 1.0f - tt;
    float w[4];
    w[0] = omt * omt * omt * (1.0f / 6.0f);                             // k=i-3
    w[1] = (3.0f * t3 - 6.0f * t2 + 4.0f) * (1.0f / 6.0f);              // k=i-2
    w[2] = (-3.0f * t3 + 3.0f * t2 + 3.0f * tt + 1.0f) * (1.0f / 6.0f); // k=i-1
    w[3] = t3 * (1.0f / 6.0f);                                          // k=i

    vf4 sf = (vf4)0.0f;
    #pragma unroll
    for (int j = 0; j < 4; ++j) {
        const int k  = i - 3 + j;
        const int kc = min(max(k, 0), N_BASES - 1);
        const float wj = (k == kc) ? w[j] : 0.0f;   // zero if clamped
        sf += wj * coeffs4[kc * ROW_VF4 + lane];    // L1-hit (6 KB table)
    }
    return sf;
}

// EXACT path: total4 == BLOCKS*THREADS*ITERS, ITERS compile-time.
template <int ITERS>
__global__ __launch_bounds__(THREADS, 8) void spline_filter_exact(
    const vf4* __restrict__ x4,
    const float* __restrict__ eigs,
    const vf4* __restrict__ coeffs4,
    vf4*       __restrict__ out4)
{
    const int gid    = blockIdx.x * THREADS + threadIdx.x;
    const int stride = BLOCKS * THREADS;       // multiple of 32
    const int lane   = gid & 31;               // iteration-invariant

    int idx = gid;
    // Pipeline prologue: prefetch iteration 0.
    float eg_n = eigs[idx >> 5];
    vf4   xv_n = __builtin_nontemporal_load(&x4[idx]);

    #pragma unroll
    for (int it = 0; it < ITERS; ++it) {
        const float eg = eg_n;
        const vf4   xv = xv_n;
        const int cur  = idx;
        idx += stride;
        if (it + 1 < ITERS) {                  // compile-time pruned on last iter
            eg_n = eigs[idx >> 5];             // issue next loads BEFORE compute:
            xv_n = __builtin_nontemporal_load(&x4[idx]);  // steady-state MLP
        }
        const vf4 sf = eval_sf(eg, lane, coeffs4);
        const vf4 o  = xv * sf * sf;
        __builtin_nontemporal_store(o, &out4[cur]);
    }
}

// Fallback for unexpected sizes: guarded grid-stride loop.
__global__ __launch_bounds__(THREADS, 8) void spline_filter_generic(
    const vf4* __restrict__ x4,
    const float* __restrict__ eigs,
    const vf4* __restrict__ coeffs4,
    vf4*       __restrict__ out4,
    int total4)
{
    const int stride = gridDim.x * THREADS;
    for (int idx = blockIdx.x * THREADS + threadIdx.x; idx < total4; idx += stride) {
        const float eg = eigs[idx >> 5];
        const vf4   xv = __builtin_nontemporal_load(&x4[idx]);
        const vf4   sf = eval_sf(eg, idx & 31, coeffs4);
        const vf4   o  = xv * sf * sf;
        __builtin_nontemporal_store(o, &out4[idx]);
    }
}

extern "C" void kernel_launch(void* const* d_in, const int* in_sizes, int n_in,
                              void* d_out, int out_size, void* d_ws, size_t ws_size,
                              hipStream_t stream) {
    const float* eval_x = (const float*)d_in[0];  // [32,8192,128] fp32
    const float* eigs   = (const float*)d_in[1];  // [32,8192]     fp32
    const float* coeffs = (const float*)d_in[2];  // [12,128]      fp32
    float* out = (float*)d_out;

    const int total4 = in_sizes[0] / 4;           // 8388608 = 2048*256*16

    if (total4 == BLOCKS * THREADS * 16) {
        spline_filter_exact<16><<<BLOCKS, THREADS, 0, stream>>>(
            (const vf4*)eval_x, eigs, (const vf4*)coeffs, (vf4*)out);
    } else {
        const int blocks = min((total4 + THREADS - 1) / THREADS, BLOCKS);
        spline_filter_generic<<<blocks, THREADS, 0, stream>>>(
            (const vf4*)eval_x, eigs, (const vf4*)coeffs, (vf4*)out, total4);
    }
}